// Round 7
// baseline (196.101 us; speedup 1.0000x reference)
//
#include <hip/hip_runtime.h>
#include <math.h>

#define HW_   128
#define CIN_  64
#define IMG_  (HW_ * HW_)       // 16384

typedef short    s16x8 __attribute__((ext_vector_type(8)));
typedef float    f32x4 __attribute__((ext_vector_type(4)));
typedef float    f32x2 __attribute__((ext_vector_type(2)));
typedef unsigned u32x4 __attribute__((ext_vector_type(4)));

__device__ __forceinline__ float bf2f(short u) {
  union { unsigned i; float f; } v;
  v.i = ((unsigned)(unsigned short)u) << 16;
  return v.f;
}
__device__ __forceinline__ short f2bf(float f) {
  union { float f; unsigned i; } v; v.f = f;
  unsigned r = (v.i + 0x7fffu + ((v.i >> 16) & 1u)) >> 16;   // RNE
  return (short)r;
}
// pack two f32 -> bf16 pair (lo = a, hi = b), RNE
__device__ __forceinline__ unsigned pk_bf16(float a, float b) {
  union { float f; unsigned u; } ua, ub; ua.f = a; ub.f = b;
  unsigned ra = ua.u + 0x7fffu + ((ua.u >> 16) & 1u);
  unsigned rb = ub.u + 0x7fffu + ((ub.u >> 16) & 1u);
  return __builtin_amdgcn_perm(rb, ra, 0x07060302u);
}
// unpack bf16 pair -> float2 {lo, hi}
__device__ __forceinline__ f32x2 up2(unsigned d) {
  union { unsigned u; float f; } lo, hi;
  lo.u = d << 16; hi.u = d & 0xffff0000u;
  return (f32x2){lo.f, hi.f};
}

// ws layout (bytes):
//   [0,       36864)    wOf bf16 [j:9][ks:2][q:4][m:32][i:8]  (A-frag order, m>=27 zero)
//   [36864,   110592)   wA  bf16 [j:9][ks:2][q:4][o:64][i:8]  (A-frag order)
//   [110592,  16887808) x_t bf16 [8][128][128][64] (NHWC)

// blocks 0..2047: NCHW f32 -> NHWC bf16 transpose; blocks 2048..: weight prep
__global__ __launch_bounds__(256) void prep_all(const float* __restrict__ x,
                                                const float* __restrict__ w_off,
                                                const float* __restrict__ w_conv,
                                                short* __restrict__ x_t,
                                                short* __restrict__ wOf,
                                                short* __restrict__ wA) {
  __shared__ float lt[64][65];
  if (blockIdx.x >= 2048) {
    int t = (blockIdx.x - 2048) * 256 + threadIdx.x;
    if (t < 36864) {
      int i = t & 7, o = (t >> 3) & 63, q = (t >> 9) & 3, ks = (t >> 11) & 1, j = t >> 12;
      int c = ks * 32 + q * 8 + i;
      wA[t] = f2bf(w_conv[o * 576 + c * 9 + j]);
    }
    if (t < 18432) {
      int i = t & 7, m = (t >> 3) & 31, q = (t >> 8) & 3, ks = (t >> 10) & 1, j = t >> 11;
      int c = ks * 32 + q * 8 + i;
      wOf[t] = (m < 27) ? f2bf(w_off[(m * 64 + c) * 9 + j]) : (short)0;
    }
    return;
  }
  int bi  = blockIdx.x >> 8;
  int hw0 = (blockIdx.x & 255) * 64;
  int t = threadIdx.x;
  const float* xb = x + bi * (CIN_ * IMG_) + hw0;
#pragma unroll
  for (int i = 0; i < 16; ++i) {
    int c = i * 4 + (t >> 6), px = t & 63;
    lt[c][px] = xb[c * IMG_ + px];
  }
  __syncthreads();
  short* ob = x_t + (size_t)(bi * IMG_ + hw0) * 64;
#pragma unroll
  for (int i = 0; i < 4; ++i) {
    int px = i * 16 + (t >> 4), c0 = (t & 15) * 4;
    unsigned lo = pk_bf16(lt[c0][px], lt[c0 + 1][px]);
    unsigned hi = pk_bf16(lt[c0 + 2][px], lt[c0 + 3][px]);
    *(uint2*)&ob[px * 64 + c0] = make_uint2(lo, hi);
  }
}

// Fused: offset-conv (MFMA) -> LDS offset exchange -> address-precomputed,
// sched_barrier-pinned pipelined deformable sample -> MFMA GEMM.
__global__ __launch_bounds__(256)
__attribute__((amdgpu_waves_per_eu(2, 4)))
void dfuse(const short* __restrict__ x_t,
           const short* __restrict__ wOf,
           const float* __restrict__ b_off,
           const short* __restrict__ wA,
           float* __restrict__ out) {
  __shared__ short obx[64 * 32];   // [px][ch0..31] bf16: o1(0-8) o2(9-17) sig(18-26)

  int bi  = blockIdx.x >> 8;
  int hw0 = (blockIdx.x & 255) * 64;
  int t   = threadIdx.x;
  int wv = t >> 6, l = t & 63;
  int col = l & 15, q = l >> 4;
  int px_local = wv * 16 + col;
  int p = hw0 + px_local;
  int h = p >> 7, w = p & 127;

  const short* xb = x_t + (size_t)bi * (IMG_ * 64);

  // ---------------- phase 1: offset conv (pinned depth-1 pipeline) --------
  {
    int      p1off[9];
    unsigned p1m[9];
#pragma unroll
    for (int j = 0; j < 9; ++j) {
      int hh = h + j / 3 - 1, ww = w + j % 3 - 1;
      bool v = (hh >= 0) && (hh < HW_) && (ww >= 0) && (ww < HW_);
      int hc = min(max(hh, 0), HW_ - 1), wc = min(max(ww, 0), HW_ - 1);
      p1off[j] = (hc * HW_ + wc) * 64 + q * 8;
      p1m[j] = v ? 0xffffffffu : 0u;
    }
    __builtin_amdgcn_sched_barrier(0);

    const short* wq = wOf + q * 256 + col * 8;
    f32x4 a0v = {0.f, 0.f, 0.f, 0.f};
    f32x4 a1v = {0.f, 0.f, 0.f, 0.f};

    u32x4 pb[2][2];
    pb[0][0] = *(const u32x4*)(xb + p1off[0]);
    pb[0][1] = *(const u32x4*)(xb + p1off[0] + 32);
#pragma unroll
    for (int j = 0; j < 9; ++j) {
      if (j < 8) {
        pb[(j + 1) & 1][0] = *(const u32x4*)(xb + p1off[j + 1]);
        pb[(j + 1) & 1][1] = *(const u32x4*)(xb + p1off[j + 1] + 32);
      }
      __builtin_amdgcn_sched_barrier(0);
      u32x4 b0u = pb[j & 1][0], b1u = pb[j & 1][1];
      unsigned m = p1m[j];
#pragma unroll
      for (int i = 0; i < 4; ++i) { b0u[i] &= m; b1u[i] &= m; }
      union { u32x4 u; s16x8 v; } B0, B1;
      B0.u = b0u; B1.u = b1u;
      const short* wj = wq + j * 2048;
      s16x8 a00 = *(const s16x8*)(wj);
      s16x8 a01 = *(const s16x8*)(wj + 128);
      s16x8 a10 = *(const s16x8*)(wj + 1024);
      s16x8 a11 = *(const s16x8*)(wj + 1024 + 128);
      a0v = __builtin_amdgcn_mfma_f32_16x16x32_bf16(a00, B0.v, a0v, 0, 0, 0);
      a1v = __builtin_amdgcn_mfma_f32_16x16x32_bf16(a01, B0.v, a1v, 0, 0, 0);
      a0v = __builtin_amdgcn_mfma_f32_16x16x32_bf16(a10, B1.v, a0v, 0, 0, 0);
      a1v = __builtin_amdgcn_mfma_f32_16x16x32_bf16(a11, B1.v, a1v, 0, 0, 0);
    }
    short* od = obx + px_local * 32;
#pragma unroll
    for (int r = 0; r < 4; ++r) {
      int ch = q * 4 + r;
      od[ch] = f2bf(a0v[r] + b_off[ch]);
    }
#pragma unroll
    for (int r = 0; r < 4; ++r) {
      int ch = 16 + q * 4 + r;
      if (ch < 27) {
        float v = a1v[r] + b_off[ch];
        if (ch >= 18) v = 1.f / (1.f + __expf(-v));
        od[ch] = f2bf(v);
      }
    }
  }
  __syncthreads();

  // ---------------- phase 2: precompute ALL tap addresses + weights --------
  int   coff[9][4];
  float cwgt[9][4];
  {
    const uint4* obw = (const uint4*)(obx + px_local * 32);
    uint4 q0 = obw[0], q1 = obw[1], q2 = obw[2], q3 = obw[3];
    unsigned ow[16] = {q0.x, q0.y, q0.z, q0.w, q1.x, q1.y, q1.z, q1.w,
                       q2.x, q2.y, q2.z, q2.w, q3.x, q3.y, q3.z, q3.w};
#pragma unroll
    for (int j = 0; j < 9; ++j) {
      const int e1 = j, e2 = 9 + j, e3 = 18 + j;
      float o1 = bf2f((short)(ow[e1 >> 1] >> ((e1 & 1) << 4)));
      float o2 = bf2f((short)(ow[e2 >> 1] >> ((e2 & 1) << 4)));
      float mk = bf2f((short)(ow[e3 >> 1] >> ((e3 & 1) << 4)));

      float pxf = o1 + (float)(w + (j % 3) - 1);
      float pyf = o2 + (float)(h + (j / 3) - 1);
      float fx = floorf(pxf), fy = floorf(pyf);
      int   x0 = (int)fx,   y0 = (int)fy;
      float ax = pxf - fx, ay = pyf - fy;
      float bx = 1.f - ax, by = 1.f - ay;

      bool vx0 = (x0 >= 0)  && (x0 < HW_);
      bool vx1 = (x0 >= -1) && (x0 < HW_ - 1);
      bool vy0 = (y0 >= 0)  && (y0 < HW_);
      bool vy1 = (y0 >= -1) && (y0 < HW_ - 1);

      cwgt[j][0] = by * bx * mk * ((vy0 && vx0) ? 1.f : 0.f);
      cwgt[j][1] = by * ax * mk * ((vy0 && vx1) ? 1.f : 0.f);
      cwgt[j][2] = ay * bx * mk * ((vy1 && vx0) ? 1.f : 0.f);
      cwgt[j][3] = ay * ax * mk * ((vy1 && vx1) ? 1.f : 0.f);

      int xc0 = min(max(x0, 0), HW_ - 1), xc1 = min(max(x0 + 1, 0), HW_ - 1);
      int yc0 = min(max(y0, 0), HW_ - 1), yc1 = min(max(y0 + 1, 0), HW_ - 1);
      coff[j][0] = (yc0 * HW_ + xc0) * 64 + q * 8;
      coff[j][1] = (yc0 * HW_ + xc1) * 64 + q * 8;
      coff[j][2] = (yc1 * HW_ + xc0) * 64 + q * 8;
      coff[j][3] = (yc1 * HW_ + xc1) * 64 + q * 8;
    }
  }
  // pin: all addresses/weights materialized BEFORE the tap loop
  __builtin_amdgcn_sched_barrier(0);

  // ---------------- phase 3: pinned depth-1 pipelined sampling + GEMM -----
  f32x4 acc[4];
#pragma unroll
  for (int ms = 0; ms < 4; ++ms) acc[ms] = (f32x4){0.f, 0.f, 0.f, 0.f};

  const short* wq = wA + q * 512 + col * 8;

  u32x4 cb[2][8];
#pragma unroll
  for (int cn = 0; cn < 4; ++cn) {
    cb[0][cn]     = *(const u32x4*)(xb + coff[0][cn]);
    cb[0][4 + cn] = *(const u32x4*)(xb + coff[0][cn] + 32);
  }

#pragma unroll
  for (int j = 0; j < 9; ++j) {
    if (j < 8) {
      // issue next tap's 8 corner loads FIRST; barrier pins them here
#pragma unroll
      for (int cn = 0; cn < 4; ++cn) {
        cb[(j + 1) & 1][cn]     = *(const u32x4*)(xb + coff[j + 1][cn]);
        cb[(j + 1) & 1][4 + cn] = *(const u32x4*)(xb + coff[j + 1][cn] + 32);
      }
    }
    __builtin_amdgcn_sched_barrier(0);

    float u0 = cwgt[j][0], u1 = cwgt[j][1], u2 = cwgt[j][2], u3 = cwgt[j][3];
    union { unsigned u[4]; s16x8 v; } F0, F1;
#pragma unroll
    for (int i = 0; i < 4; ++i) {
      f32x2 v0 = up2(cb[j & 1][0][i]) * u0;
      v0 += up2(cb[j & 1][1][i]) * u1;
      v0 += up2(cb[j & 1][2][i]) * u2;
      v0 += up2(cb[j & 1][3][i]) * u3;
      F0.u[i] = pk_bf16(v0.x, v0.y);
      f32x2 v1 = up2(cb[j & 1][4][i]) * u0;
      v1 += up2(cb[j & 1][5][i]) * u1;
      v1 += up2(cb[j & 1][6][i]) * u2;
      v1 += up2(cb[j & 1][7][i]) * u3;
      F1.u[i] = pk_bf16(v1.x, v1.y);
    }

    const short* wj = wq + j * 4096;
#pragma unroll
    for (int ms = 0; ms < 4; ++ms) {
      s16x8 a0 = *(const s16x8*)(wj + ms * 128);
      acc[ms] = __builtin_amdgcn_mfma_f32_16x16x32_bf16(a0, F0.v, acc[ms], 0, 0, 0);
    }
#pragma unroll
    for (int ms = 0; ms < 4; ++ms) {
      s16x8 a1 = *(const s16x8*)(wj + 2048 + ms * 128);
      acc[ms] = __builtin_amdgcn_mfma_f32_16x16x32_bf16(a1, F1.v, acc[ms], 0, 0, 0);
    }
  }

  float* op = out + (size_t)bi * (CIN_ * IMG_) + p;
#pragma unroll
  for (int ms = 0; ms < 4; ++ms)
#pragma unroll
    for (int r = 0; r < 4; ++r)
      op[(ms * 16 + q * 4 + r) * IMG_] = acc[ms][r];
}

extern "C" void kernel_launch(void* const* d_in, const int* in_sizes, int n_in,
                              void* d_out, int out_size, void* d_ws, size_t ws_size,
                              hipStream_t stream) {
  const float* x      = (const float*)d_in[0];
  const float* w_off  = (const float*)d_in[1];
  const float* b_off  = (const float*)d_in[2];
  const float* w_conv = (const float*)d_in[3];
  float* out = (float*)d_out;

  char* ws = (char*)d_ws;
  short* wOf = (short*)(ws);
  short* wA  = (short*)(ws + 36864);
  short* x_t = (short*)(ws + 110592);

  hipLaunchKernelGGL(prep_all, dim3(2192), dim3(256), 0, stream, x, w_off, w_conv, x_t, wOf, wA);
  hipLaunchKernelGGL(dfuse,    dim3(2048), dim3(256), 0, stream, x_t, wOf, b_off, wA, out);
}

// Round 8
// 147.238 us; speedup vs baseline: 1.3319x; 1.3319x over previous
//
#include <hip/hip_runtime.h>
#include <math.h>

#define HW_   128
#define CIN_  64
#define IMG_  (HW_ * HW_)       // 16384

#define TR_    5                // tile rows  [h-2 .. h+2]
#define TC_    72               // tile cols  [w0-4 .. w0+67]
#define PIT_   36               // dwords per pixel (64ch bf16 = 32 dw + 4 pad)
#define TILEDW (TR_ * TC_ * PIT_)   // 12960 dw = 51840 B

typedef short    s16x8 __attribute__((ext_vector_type(8)));
typedef float    f32x4 __attribute__((ext_vector_type(4)));
typedef float    f32x2 __attribute__((ext_vector_type(2)));
typedef unsigned u32x4 __attribute__((ext_vector_type(4)));

__device__ __forceinline__ short f2bf(float f) {
  union { float f; unsigned i; } v; v.f = f;
  unsigned r = (v.i + 0x7fffu + ((v.i >> 16) & 1u)) >> 16;   // RNE
  return (short)r;
}

#if defined(__has_builtin)
#if __has_builtin(__builtin_amdgcn_cvt_pk_bf16_f32)
#define HAVE_CVT_PK_BF16 1
#endif
#endif

// pack two f32 -> bf16 pair (lo=a, hi=b)
__device__ __forceinline__ unsigned PK2(float a, float b) {
#ifdef HAVE_CVT_PK_BF16
  typedef __bf16 bf16x2_t __attribute__((ext_vector_type(2)));
  union { bf16x2_t v; unsigned u; } cv;
  cv.v = __builtin_amdgcn_cvt_pk_bf16_f32(a, b);
  return cv.u;
#else
  union { float f; unsigned u; } ua, ub; ua.f = a; ub.f = b;
  unsigned ra = ua.u + 0x7fffu + ((ua.u >> 16) & 1u);
  unsigned rb = ub.u + 0x7fffu + ((ub.u >> 16) & 1u);
  return __builtin_amdgcn_perm(rb, ra, 0x07060302u);
#endif
}
// unpack bf16 pair -> float2 {lo, hi}
__device__ __forceinline__ f32x2 up2(unsigned d) {
  union { unsigned u; float f; } lo, hi;
  lo.u = d << 16; hi.u = d & 0xffff0000u;
  return (f32x2){lo.f, hi.f};
}

// ws layout (bytes):
//   [0,     36864)  wOf bf16 [j:9][ks:2][q:4][m:32][i:8]  (A-frag order, m>=27 zero)
//   [36864, 110592) wA  bf16 [j:9][ks:2][q:4][o:64][i:8]  (A-frag order)

__global__ __launch_bounds__(256) void wprep(const float* __restrict__ w_off,
                                             const float* __restrict__ w_conv,
                                             short* __restrict__ wOf,
                                             short* __restrict__ wA) {
  int t = blockIdx.x * 256 + threadIdx.x;
  if (t < 36864) {
    int i = t & 7, o = (t >> 3) & 63, q = (t >> 9) & 3, ks = (t >> 11) & 1, j = t >> 12;
    int c = ks * 32 + q * 8 + i;
    wA[t] = f2bf(w_conv[o * 576 + c * 9 + j]);
  }
  if (t < 18432) {
    int i = t & 7, m = (t >> 3) & 31, q = (t >> 8) & 3, ks = (t >> 10) & 1, j = t >> 11;
    int c = ks * 32 + q * 8 + i;
    wOf[t] = (m < 27) ? f2bf(w_off[(m * 64 + c) * 9 + j]) : (short)0;
  }
}

// Fully fused: stage f32 NCHW -> bf16 NHWC halo tile in LDS (one barrier),
// offset conv (MFMA from tile), shuffle-exchange offsets (no barrier),
// LDS-gather deformable sampling + MFMA GEMM (global fallback for |o|>=1).
__global__ __launch_bounds__(256)
__attribute__((amdgpu_waves_per_eu(3)))
void dfuse(const float* __restrict__ x,
           const short* __restrict__ wOf,
           const float* __restrict__ b_off,
           const short* __restrict__ wA,
           float* __restrict__ out) {
  __shared__ __align__(16) unsigned lds_[TILEDW];

  int bi  = blockIdx.x >> 8;
  int hw0 = (blockIdx.x & 255) * 64;
  int h   = hw0 >> 7;
  int w0  = hw0 & 127;
  int t   = threadIdx.x;
  int wv  = t >> 6, l = t & 63;
  int col = l & 15, q = l >> 4;
  int px_local = wv * 16 + col;
  int p = hw0 + px_local;
  int w = w0 + px_local;

  const float* xB = x + (size_t)bi * (CIN_ * IMG_);

  // ---- stage halo tile: rows h-2..h+2, cols w0-4..w0+67, 64 ch bf16 ----
  // unit = (row r, ch-pair cp, col-chunk cc of 4 px); cc fastest => coalesced
  for (int u = t; u < TR_ * 32 * 18; u += 256) {     // 2880 units
    int cc = u % 18;
    int rc = u / 18;
    int cp = rc & 31;
    int r  = rc >> 5;
    int y  = h - 2 + r;
    int ys = min(max(y, 0), HW_ - 1);
    int xg0 = w0 - 4 + cc * 4;
    int xs  = min(max(xg0, 0), HW_ - 4);             // stays 16B-aligned
    const float* s0 = xB + (2 * cp) * IMG_ + ys * HW_ + xs;
    float4 f0 = *(const float4*)s0;                  // ch 2cp
    float4 f1 = *(const float4*)(s0 + IMG_);         // ch 2cp+1
    int sd = ((ys - (h - 2)) * TC_ + (xs - (w0 - 4))) * PIT_ + cp;
    lds_[sd]            = PK2(f0.x, f1.x);
    lds_[sd + PIT_]     = PK2(f0.y, f1.y);
    lds_[sd + 2 * PIT_] = PK2(f0.z, f1.z);
    lds_[sd + 3 * PIT_] = PK2(f0.w, f1.w);
  }
  __syncthreads();

  // ---- phase 1: offset conv from tile ----
  float oall[32];
  {
    const short* wq = wOf + q * 256 + col * 8;
    f32x4 a0v = {0.f, 0.f, 0.f, 0.f};
    f32x4 a1v = {0.f, 0.f, 0.f, 0.f};
#pragma unroll
    for (int j = 0; j < 9; ++j) {
      int dy = j / 3 - 1, dx = j % 3 - 1;
      int hh = h + dy, ww = w + dx;
      unsigned m = (hh >= 0 && hh < HW_ && ww >= 0 && ww < HW_) ? 0xffffffffu : 0u;
      const unsigned* tp = &lds_[((dy + 2) * TC_ + (px_local + dx + 4)) * PIT_ + q * 4];
      u32x4 b0u = *(const u32x4*)tp;
      u32x4 b1u = *(const u32x4*)(tp + 16);
#pragma unroll
      for (int i = 0; i < 4; ++i) { b0u[i] &= m; b1u[i] &= m; }
      union { u32x4 u; s16x8 v; } B0, B1;
      B0.u = b0u; B1.u = b1u;
      const short* wj = wq + j * 2048;
      s16x8 a00 = *(const s16x8*)(wj);
      s16x8 a01 = *(const s16x8*)(wj + 128);
      s16x8 a10 = *(const s16x8*)(wj + 1024);
      s16x8 a11 = *(const s16x8*)(wj + 1024 + 128);
      a0v = __builtin_amdgcn_mfma_f32_16x16x32_bf16(a00, B0.v, a0v, 0, 0, 0);
      a1v = __builtin_amdgcn_mfma_f32_16x16x32_bf16(a01, B0.v, a1v, 0, 0, 0);
      a0v = __builtin_amdgcn_mfma_f32_16x16x32_bf16(a10, B1.v, a0v, 0, 0, 0);
      a1v = __builtin_amdgcn_mfma_f32_16x16x32_bf16(a11, B1.v, a1v, 0, 0, 0);
    }
    // bias + sigmoid by producer lanes, then wave-local shuffle exchange
    float myv[8];
#pragma unroll
    for (int r = 0; r < 4; ++r) myv[r] = a0v[r] + b_off[q * 4 + r];
#pragma unroll
    for (int r = 0; r < 4; ++r) {
      int ch = 16 + q * 4 + r;
      float bo = b_off[min(ch, 26)];
      float v = a1v[r] + bo;
      myv[4 + r] = (ch >= 18) ? (1.f / (1.f + __expf(-v))) : v;
    }
#pragma unroll
    for (int qq = 0; qq < 4; ++qq) {
      int src = qq * 16 + col;
#pragma unroll
      for (int r = 0; r < 4; ++r) {
        oall[qq * 4 + r]      = __shfl(myv[r], src);
        oall[16 + qq * 4 + r] = __shfl(myv[4 + r], src);
      }
    }
  }

  // ---- phase 3: LDS-gather sampling + MFMA GEMM ----
  f32x4 acc[4];
#pragma unroll
  for (int ms = 0; ms < 4; ++ms) acc[ms] = (f32x4){0.f, 0.f, 0.f, 0.f};

  const short* wq = wA + q * 512 + col * 8;

#pragma unroll
  for (int j = 0; j < 9; ++j) {
    float o1 = oall[j], o2 = oall[9 + j], mk = oall[18 + j];

    float pxf = o1 + (float)(w + (j % 3) - 1);
    float pyf = o2 + (float)(h + (j / 3) - 1);
    float fx = floorf(pxf), fy = floorf(pyf);
    int   x0 = (int)fx,   y0 = (int)fy;
    float ax = pxf - fx, ay = pyf - fy;
    float bx = 1.f - ax, by = 1.f - ay;

    bool vx0 = (x0 >= 0)  && (x0 < HW_);
    bool vx1 = (x0 >= -1) && (x0 < HW_ - 1);
    bool vy0 = (y0 >= 0)  && (y0 < HW_);
    bool vy1 = (y0 >= -1) && (y0 < HW_ - 1);

    float u00 = by * bx * mk * ((vy0 && vx0) ? 1.f : 0.f);
    float u01 = by * ax * mk * ((vy0 && vx1) ? 1.f : 0.f);
    float u10 = ay * bx * mk * ((vy1 && vx0) ? 1.f : 0.f);
    float u11 = ay * ax * mk * ((vy1 && vx1) ? 1.f : 0.f);

    int xc0 = min(max(x0, 0), HW_ - 1), xc1 = min(max(x0 + 1, 0), HW_ - 1);
    int yc0 = min(max(y0, 0), HW_ - 1), yc1 = min(max(y0 + 1, 0), HW_ - 1);

    unsigned F0u[4], F1u[4];
    bool intile = (o1 >= -1.f) && (o1 < 1.f) && (o2 >= -1.f) && (o2 < 1.f);
    if (intile) {
      int r0 = yc0 - (h - 2),  r1 = yc1 - (h - 2);
      int c0 = xc0 - (w0 - 4), c1 = xc1 - (w0 - 4);
      const unsigned* t00 = &lds_[(r0 * TC_ + c0) * PIT_ + q * 4];
      const unsigned* t01 = &lds_[(r0 * TC_ + c1) * PIT_ + q * 4];
      const unsigned* t10 = &lds_[(r1 * TC_ + c0) * PIT_ + q * 4];
      const unsigned* t11 = &lds_[(r1 * TC_ + c1) * PIT_ + q * 4];
      u32x4 A00 = *(const u32x4*)t00, B00 = *(const u32x4*)(t00 + 16);
      u32x4 A01 = *(const u32x4*)t01, B01 = *(const u32x4*)(t01 + 16);
      u32x4 A10 = *(const u32x4*)t10, B10 = *(const u32x4*)(t10 + 16);
      u32x4 A11 = *(const u32x4*)t11, B11 = *(const u32x4*)(t11 + 16);
#pragma unroll
      for (int i = 0; i < 4; ++i) {
        f32x2 v0 = up2(A00[i]) * u00;
        v0 += up2(A01[i]) * u01;
        v0 += up2(A10[i]) * u10;
        v0 += up2(A11[i]) * u11;
        F0u[i] = PK2(v0.x, v0.y);
        f32x2 v1 = up2(B00[i]) * u00;
        v1 += up2(B01[i]) * u01;
        v1 += up2(B10[i]) * u10;
        v1 += up2(B11[i]) * u11;
        F1u[i] = PK2(v1.x, v1.y);
      }
    } else {
      // rare fallback: gather straight from f32 NCHW x
      int g00 = yc0 * HW_ + xc0, g01 = yc0 * HW_ + xc1;
      int g10 = yc1 * HW_ + xc0, g11 = yc1 * HW_ + xc1;
      for (int hB = 0; hB < 2; ++hB) {
        for (int ii = 0; ii < 4; ++ii) {
          int c0 = hB * 32 + q * 8 + 2 * ii;
          const float* pc = xB + c0 * IMG_;
          const float* pd = pc + IMG_;
          float va = u00 * pc[g00] + u01 * pc[g01] + u10 * pc[g10] + u11 * pc[g11];
          float vb = u00 * pd[g00] + u01 * pd[g01] + u10 * pd[g10] + u11 * pd[g11];
          if (hB) F1u[ii] = PK2(va, vb); else F0u[ii] = PK2(va, vb);
        }
      }
    }

    union { unsigned u[4]; s16x8 v; } F0, F1;
#pragma unroll
    for (int i = 0; i < 4; ++i) { F0.u[i] = F0u[i]; F1.u[i] = F1u[i]; }

    const short* wj = wq + j * 4096;
#pragma unroll
    for (int ms = 0; ms < 4; ++ms) {
      s16x8 a0 = *(const s16x8*)(wj + ms * 128);
      acc[ms] = __builtin_amdgcn_mfma_f32_16x16x32_bf16(a0, F0.v, acc[ms], 0, 0, 0);
    }
#pragma unroll
    for (int ms = 0; ms < 4; ++ms) {
      s16x8 a1 = *(const s16x8*)(wj + 2048 + ms * 128);
      acc[ms] = __builtin_amdgcn_mfma_f32_16x16x32_bf16(a1, F1.v, acc[ms], 0, 0, 0);
    }
  }

  float* op = out + (size_t)bi * (CIN_ * IMG_) + p;
#pragma unroll
  for (int ms = 0; ms < 4; ++ms)
#pragma unroll
    for (int r = 0; r < 4; ++r)
      op[(ms * 16 + q * 4 + r) * IMG_] = acc[ms][r];
}

extern "C" void kernel_launch(void* const* d_in, const int* in_sizes, int n_in,
                              void* d_out, int out_size, void* d_ws, size_t ws_size,
                              hipStream_t stream) {
  const float* x      = (const float*)d_in[0];
  const float* w_off  = (const float*)d_in[1];
  const float* b_off  = (const float*)d_in[2];
  const float* w_conv = (const float*)d_in[3];
  float* out = (float*)d_out;

  char* ws = (char*)d_ws;
  short* wOf = (short*)(ws);
  short* wA  = (short*)(ws + 36864);

  hipLaunchKernelGGL(wprep, dim3(144),  dim3(256), 0, stream, w_off, w_conv, wOf, wA);
  hipLaunchKernelGGL(dfuse, dim3(2048), dim3(256), 0, stream, x, wOf, b_off, wA, out);
}